// Round 1
// baseline (634.550 us; speedup 1.0000x reference)
//
#include <hip/hip_runtime.h>
#include <hip/hip_fp16.h>

// Problem constants (fixed by reference)
#define N_PTS 1048576
#define BSEG  2048
#define XSTR  72    // xf f16 row stride: 64 feats + 8 pad (144 B = 16*9, bank shift 4/row)
#define HSTR  136   // h  f16 row stride: 128 + 8 pad   (272 B = 16*17, bank shift 4/row)

typedef _Float16 half8  __attribute__((ext_vector_type(8)));
typedef _Float16 half4  __attribute__((ext_vector_type(4)));
typedef float    floatx4 __attribute__((ext_vector_type(4)));

// ---------------------------------------------------------------------------
// Kernel W: transpose + f16-convert heavy-layer weights.
// w1T[j][k] = W1[32+k][j] (feature rows; enc rows folded into per-seg bias).
// w2T/w3T: [128 j][128 k].
// ---------------------------------------------------------------------------
__global__ __launch_bounds__(256) void wconv(const float* __restrict__ w1,
                                             const float* __restrict__ w2,
                                             const float* __restrict__ w3,
                                             _Float16* __restrict__ w1T,
                                             _Float16* __restrict__ w2T,
                                             _Float16* __restrict__ w3T) {
    int idx = blockIdx.x * 256 + threadIdx.x;
    if (idx < 8192) {                         // 128*64
        int j = idx >> 6, k = idx & 63;
        w1T[idx] = (_Float16)w1[(32 + k) * 128 + j];
    } else if (idx < 8192 + 16384) {
        int i = idx - 8192; int j = i >> 7, k = i & 127;
        w2T[i] = (_Float16)w2[k * 128 + j];
    } else if (idx < 8192 + 32768) {
        int i = idx - 8192 - 16384; int j = i >> 7, k = i & 127;
        w3T[i] = (_Float16)w3[k * 128 + j];
    }
}

// ---------------------------------------------------------------------------
// Mega kernel: per-segment encoder + pool + bias-fold + 3-layer f16 MFMA MLP
// + segment max + fp32 head. One block per segment.
//
// MFMA layers computed TRANSPOSED: D = W^T (A) * x^T (B), so each lane holds
// point-row = lane&15 and 4 consecutive output features per quad. h writes are
// single half4 ds_write_b64 (no cross-lane shuffle); biases live in the MFMA
// C-in; relu of L3 folds into the >=0 running max. h rows padded to 136 halfs
// (272 B stride -> 4-bank shift/row: reads 2-way=free). w2/w3 frags stream
// from L2-hot global each iter so they don't pin 64 VGPRs.
// ---------------------------------------------------------------------------
__global__ __launch_bounds__(256, 4) void fused_all(
    const float* __restrict__ pts, const float* __restrict__ feat,
    const int* __restrict__ batch,
    const float* __restrict__ wne, const float* __restrict__ bne,
    const float* __restrict__ w1, const float* __restrict__ b1,
    const _Float16* __restrict__ w1T, const _Float16* __restrict__ w2T,
    const _Float16* __restrict__ w3T,
    const float* __restrict__ b2, const float* __restrict__ b3,
    const float* __restrict__ wg1, const float* __restrict__ bg1,
    const float* __restrict__ wg2, const float* __restrict__ bg2,
    const float* __restrict__ wg3, const float* __restrict__ bg3,
    float* __restrict__ out)
{
    __shared__ __attribute__((aligned(16))) _Float16 xf[2][16 * XSTR]; // 4.6 KB
    __shared__ __attribute__((aligned(16))) _Float16 h1s[16 * HSTR];   // 4.25 KB
    __shared__ __attribute__((aligned(16))) _Float16 h2s[16 * HSTR];   // 4.25 KB
    __shared__ __attribute__((aligned(16))) float b1ps[128];
    __shared__ __attribute__((aligned(16))) float pooled[128];
    __shared__ float g1s[128];
    __shared__ float g2s[64];
    __shared__ float swne[96];
    __shared__ float sbne[32];
    __shared__ float sEnc[32];
    __shared__ float red16[16][33];  // +1 pad: conflict-free quad-leader writes

    const int b = blockIdx.x, tid = threadIdx.x;
    const int lane = tid & 63, jq = tid >> 6;
    const int l15 = lane & 15, quad = lane >> 4;

    if (tid < 96) swne[tid] = wne[tid];
    if (tid < 32) sbne[tid] = bne[tid];

    // segment range (batch sorted)
    int lo = 0, hi = N_PTS;
    while (lo < hi) { int mid = (lo + hi) >> 1; if (batch[mid] < b) lo = mid + 1; else hi = mid; }
    const int start = __builtin_amdgcn_readfirstlane(lo);
    hi = N_PTS;
    while (lo < hi) { int mid = (lo + hi) >> 1; if (batch[mid] < b + 1) lo = mid + 1; else hi = mid; }
    const int end = __builtin_amdgcn_readfirstlane(lo);
    const int n = end - start;
    const int niter = (n + 15) >> 4;
    __syncthreads();

    // ---- encoder + segment max (relu>=0 so init-0 max == neginf->0 guard) ----
    {
        float mx[32];
#pragma unroll
        for (int j = 0; j < 32; j++) mx[j] = 0.f;
        for (int p = start + tid; p < end; p += 256) {
            float x0 = pts[3 * p], x1 = pts[3 * p + 1], x2 = pts[3 * p + 2];
#pragma unroll
            for (int j = 0; j < 32; j++) {
                float e = fmaf(x0, swne[j], fmaf(x1, swne[32 + j], fmaf(x2, swne[64 + j], sbne[j])));
                mx[j] = fmaxf(mx[j], e);
            }
        }
        // in-quad reduce (4 levels), quad leaders -> LDS, final 16-way in LDS
#pragma unroll
        for (int j = 0; j < 32; j++) {
#pragma unroll
            for (int off = 1; off < 16; off <<= 1)
                mx[j] = fmaxf(mx[j], __shfl_xor(mx[j], off, 64));
        }
        if (l15 == 0) {
            const int qi = tid >> 4;   // 0..15
#pragma unroll
            for (int j = 0; j < 32; j++) red16[qi][j] = mx[j];
        }
        __syncthreads();
        if (tid < 32) {
            float m = red16[0][tid];
#pragma unroll
            for (int q = 1; q < 16; q++) m = fmaxf(m, red16[q][tid]);
            sEnc[tid] = m;
        }
        __syncthreads();
        // fold enc through W1's enc rows into per-segment bias (fp32 exact)
        if (tid < 128) {
            float acc = b1[tid];
#pragma unroll 8
            for (int k = 0; k < 32; k++) acc = fmaf(sEnc[k], w1[k * 128 + tid], acc);
            b1ps[tid] = acc;
        }
    }

    // ---- resident L1 weight frags (A operand: row = j = jc, k = quad*8+t) ----
    const int jc0 = jq * 32 + l15, jc1 = jc0 + 16;
    half8 w1f[2][2];
#pragma unroll
    for (int ks = 0; ks < 2; ks++) {
        w1f[0][ks] = *(const half8*)(w1T + jc0 * 64 + ks * 32 + quad * 8);
        w1f[1][ks] = *(const half8*)(w1T + jc1 * 64 + ks * 32 + quad * 8);
    }
    // per-lane bias quads: acc[jt][i] <-> feature j = jq*32 + jt*16 + quad*4 + i
    const int j0 = jq * 32 + quad * 4;
    floatx4 bb2[2], bb3[2];
    bb2[0] = *(const floatx4*)(b2 + j0); bb2[1] = *(const floatx4*)(b2 + j0 + 16);
    bb3[0] = *(const floatx4*)(b3 + j0); bb3[1] = *(const floatx4*)(b3 + j0 + 16);

    // staging: 1 float4/thread/iter (16 rows x 64 f32)
    const int srow = tid >> 4, scol = tid & 15;
    floatx4 pf;
    auto issue = [&](int it) {
        int p = start + it * 16 + srow;
        if (p < end) pf = *(const floatx4*)(feat + (size_t)p * 64 + scol * 4);
        else         pf = (floatx4){0.f, 0.f, 0.f, 0.f};
    };
    auto commit = [&](int buf) {
        half4 hv = {(_Float16)pf.x, (_Float16)pf.y, (_Float16)pf.z, (_Float16)pf.w};
        *(half4*)(&xf[buf][srow * XSTR + scol * 4]) = hv;
    };
    // transposed-output store: lane holds row=l15, 4 consecutive cols -> 1 b64
    auto storeH = [&](_Float16* hbuf, floatx4* acc) {
#pragma unroll
        for (int jt = 0; jt < 2; jt++) {
            half4 hv = {(_Float16)fmaxf(acc[jt][0], 0.f), (_Float16)fmaxf(acc[jt][1], 0.f),
                        (_Float16)fmaxf(acc[jt][2], 0.f), (_Float16)fmaxf(acc[jt][3], 0.f)};
            *(half4*)(&hbuf[l15 * HSTR + jt * 16 + j0]) = hv;
        }
    };

    if (niter > 0) { issue(0); commit(0); if (niter > 1) issue(1); }
    __syncthreads();   // covers b1ps + xf[0]

    floatx4 bb1[2];
    bb1[0] = *(const floatx4*)(b1ps + j0); bb1[1] = *(const floatx4*)(b1ps + j0 + 16);

    floatx4 vm[2];
#pragma unroll
    for (int i = 0; i < 4; i++) { vm[0][i] = 0.f; vm[1][i] = 0.f; }

    for (int it = 0; it < niter; it++) {
        const int buf = it & 1;
        // stream w2 frags (L2-hot, ~300cy of L1 compute to hide latency)
        half8 wf[2][4];
#pragma unroll
        for (int ks = 0; ks < 4; ks++) {
            wf[0][ks] = *(const half8*)(w2T + jc0 * 128 + ks * 32 + quad * 8);
            wf[1][ks] = *(const half8*)(w2T + jc1 * 128 + ks * 32 + quad * 8);
        }
        floatx4 acc[2];

        // ---- Layer 1: D = W1^T * x^T (K=64), bias in C-in ----
        acc[0] = bb1[0]; acc[1] = bb1[1];
#pragma unroll
        for (int ks = 0; ks < 2; ks++) {
            half8 a = *(const half8*)(&xf[buf][l15 * XSTR + ks * 32 + quad * 8]);
            acc[0] = __builtin_amdgcn_mfma_f32_16x16x32_f16(w1f[0][ks], a, acc[0], 0, 0, 0);
            acc[1] = __builtin_amdgcn_mfma_f32_16x16x32_f16(w1f[1][ks], a, acc[1], 0, 0, 0);
        }
        storeH(h1s, acc);
        __syncthreads();   // B1: h1 ready

        // ---- Layer 2 (K=128) ----
        acc[0] = bb2[0]; acc[1] = bb2[1];
#pragma unroll
        for (int ks = 0; ks < 4; ks++) {
            half8 a = *(const half8*)(&h1s[l15 * HSTR + ks * 32 + quad * 8]);
            acc[0] = __builtin_amdgcn_mfma_f32_16x16x32_f16(wf[0][ks], a, acc[0], 0, 0, 0);
            acc[1] = __builtin_amdgcn_mfma_f32_16x16x32_f16(wf[1][ks], a, acc[1], 0, 0, 0);
        }
        // stream w3 frags into the same regs (dead after last L2 mfma)
#pragma unroll
        for (int ks = 0; ks < 4; ks++) {
            wf[0][ks] = *(const half8*)(w3T + jc0 * 128 + ks * 32 + quad * 8);
            wf[1][ks] = *(const half8*)(w3T + jc1 * 128 + ks * 32 + quad * 8);
        }
        storeH(h2s, acc);
        if (it + 1 < niter) { commit(buf ^ 1); if (it + 2 < niter) issue(it + 2); }
        __syncthreads();   // B2: h2 + next x ready

        // ---- Layer 3 (K=128) -> running max (relu folded: vm>=0) ----
        acc[0] = bb3[0]; acc[1] = bb3[1];
#pragma unroll
        for (int ks = 0; ks < 4; ks++) {
            half8 a = *(const half8*)(&h2s[l15 * HSTR + ks * 32 + quad * 8]);
            acc[0] = __builtin_amdgcn_mfma_f32_16x16x32_f16(wf[0][ks], a, acc[0], 0, 0, 0);
            acc[1] = __builtin_amdgcn_mfma_f32_16x16x32_f16(wf[1][ks], a, acc[1], 0, 0, 0);
        }
        if (it * 16 + l15 < n) {   // lane-uniform row mask (row = point = l15)
#pragma unroll
            for (int i = 0; i < 4; i++) {
                vm[0][i] = fmaxf(vm[0][i], acc[0][i]);
                vm[1][i] = fmaxf(vm[1][i], acc[1][i]);
            }
        }
        // no barrier: h2 reuse fenced by next B1 (reads pre-B1, writes post-B1)
    }

    // reduce over the 16 point-lanes of each quad; each feature owned by one
    // (wave,quad) -> plain vector store
#pragma unroll
    for (int jt = 0; jt < 2; jt++) {
#pragma unroll
        for (int off = 1; off < 16; off <<= 1) {
#pragma unroll
            for (int i = 0; i < 4; i++)
                vm[jt][i] = fmaxf(vm[jt][i], __shfl_xor(vm[jt][i], off, 64));
        }
    }
    if (l15 == 0) {
        *(floatx4*)(pooled + j0)      = vm[0];
        *(floatx4*)(pooled + j0 + 16) = vm[1];
    }
    __syncthreads();

    // ---- fp32 head MLP (tiny, exact) ----
    if (tid < 128) {
        float acc = bg1[tid];
#pragma unroll 8
        for (int k = 0; k < 128; k++) acc = fmaf(pooled[k], wg1[k * 128 + tid], acc);
        g1s[tid] = fmaxf(acc, 0.f);
    }
    __syncthreads();
    if (tid < 64) {
        float acc = bg2[tid];
#pragma unroll 8
        for (int k = 0; k < 128; k++) acc = fmaf(g1s[k], wg2[k * 64 + tid], acc);
        g2s[tid] = fmaxf(acc, 0.f);
    }
    __syncthreads();
    if (tid < 32) {
        float acc = bg3[tid];
#pragma unroll 8
        for (int k = 0; k < 64; k++) acc = fmaf(g2s[k], wg3[k * 32 + tid], acc);
        out[b * 32 + tid] = fmaxf(acc, 0.f);
    }
}

// ---------------------------------------------------------------------------
extern "C" void kernel_launch(void* const* d_in, const int* in_sizes, int n_in,
                              void* d_out, int out_size, void* d_ws, size_t ws_size,
                              hipStream_t stream) {
    const float* points = (const float*)d_in[0];
    const float* feat   = (const float*)d_in[1];
    const int*   batch  = (const int*)d_in[2];
    const float* w_ne   = (const float*)d_in[3];
    const float* b_ne   = (const float*)d_in[4];
    const float* w1  = (const float*)d_in[5];
    const float* b1  = (const float*)d_in[6];
    const float* w2  = (const float*)d_in[7];
    const float* b2  = (const float*)d_in[8];
    const float* w3  = (const float*)d_in[9];
    const float* b3  = (const float*)d_in[10];
    const float* wg1 = (const float*)d_in[11];
    const float* bg1 = (const float*)d_in[12];
    const float* wg2 = (const float*)d_in[13];
    const float* bg2 = (const float*)d_in[14];
    const float* wg3 = (const float*)d_in[15];
    const float* bg3 = (const float*)d_in[16];
    float* out = (float*)d_out;

    char* ws = (char*)d_ws;
    _Float16* w1T = (_Float16*)ws;                   // 8192  halfs = 16 KiB
    _Float16* w2T = (_Float16*)(ws + 16384);         // 16384 halfs = 32 KiB
    _Float16* w3T = (_Float16*)(ws + 49152);         // 16384 halfs = 32 KiB

    wconv<<<160, 256, 0, stream>>>(w1, w2, w3, w1T, w2T, w3T);
    fused_all<<<BSEG, 256, 0, stream>>>(points, feat, batch, w_ne, b_ne, w1, b1,
                                        w1T, w2T, w3T, b2, b3,
                                        wg1, bg1, wg2, bg2, wg3, bg3, out);
}

// Round 3
// 498.463 us; speedup vs baseline: 1.2730x; 1.2730x over previous
//
#include <hip/hip_runtime.h>
#include <hip/hip_fp16.h>

// Problem constants (fixed by reference)
#define N_PTS 1048576
#define BSEG  2048
#define XSTR  72    // xf f16 row stride: 64 feats + 8 pad (144 B, bank shift 4/row)

typedef _Float16 half8  __attribute__((ext_vector_type(8)));
typedef _Float16 half4  __attribute__((ext_vector_type(4)));
typedef float    floatx4 __attribute__((ext_vector_type(4)));

// ---------------------------------------------------------------------------
// Kernel W: transpose + f16-convert heavy-layer weights, and precompute the
// segment boundary table seg[0..2048] (batch is sorted).
// Index ranges (ROUND-2 BUG FIX: seg branch base was 57344, writing seg[-16384
// ..-1] = zeroing w2T/w3T; correct base is 40960):
//   [0,     8192): w1T   [8192, 24576): w2T
//   [24576,40960): w3T   [40960,43009): seg
// ---------------------------------------------------------------------------
__global__ __launch_bounds__(256) void wconv(const float* __restrict__ w1,
                                             const float* __restrict__ w2,
                                             const float* __restrict__ w3,
                                             const int* __restrict__ batch,
                                             _Float16* __restrict__ w1T,
                                             _Float16* __restrict__ w2T,
                                             _Float16* __restrict__ w3T,
                                             int* __restrict__ seg) {
    int idx = blockIdx.x * 256 + threadIdx.x;
    if (idx < 8192) {                         // 128*64
        int j = idx >> 6, k = idx & 63;
        w1T[idx] = (_Float16)w1[(32 + k) * 128 + j];
    } else if (idx < 24576) {
        int i = idx - 8192; int j = i >> 7, k = i & 127;
        w2T[i] = (_Float16)w2[k * 128 + j];
    } else if (idx < 40960) {
        int i = idx - 24576; int j = i >> 7, k = i & 127;
        w3T[i] = (_Float16)w3[k * 128 + j];
    } else if (idx < 40960 + 2049) {
        int b = idx - 40960;
        if (b == 2048) {
            seg[2048] = N_PTS;
        } else {
            int lo = 0, hi = N_PTS;
            while (lo < hi) { int mid = (lo + hi) >> 1; if (batch[mid] < b) lo = mid + 1; else hi = mid; }
            seg[b] = lo;
        }
    }
}

// ---------------------------------------------------------------------------
// Mega kernel: per-segment encoder + pool + bias-fold + 3-layer f16 MFMA MLP
// + segment max + fp32 head. One block per segment, 4 waves.
//
// MFMA layers computed TRANSPOSED: D = W^T (A) * x^T (B). Each lane holds
// point = lane&15 (output col) and 4 consecutive features per quad (rows).
// h stores are a single half4 into the XOR chunk-swizzled [16][128] layout;
// reads use the matching swizzle (bank-optimal: verified bijection, e.g.
// (row3,feat37) -> addr 445 both sides). Biases ride in the MFMA C-in; L3
// relu folds into the >=0 running max. w1f/w2f/w3f VGPR-resident (80 regs).
// __launch_bounds__(256,3): ~170 VGPR cap, est. ~153 live -> no spill
// (round-1 lesson: (256,4)=128 cap spilled -> 223 MB scratch writes).
// ---------------------------------------------------------------------------
__global__ __launch_bounds__(256, 3) void fused_all(
    const float* __restrict__ pts, const float* __restrict__ feat,
    const int* __restrict__ seg,
    const float* __restrict__ wne, const float* __restrict__ bne,
    const float* __restrict__ w1, const float* __restrict__ b1,
    const _Float16* __restrict__ w1T, const _Float16* __restrict__ w2T,
    const _Float16* __restrict__ w3T,
    const float* __restrict__ b2, const float* __restrict__ b3,
    const float* __restrict__ wg1, const float* __restrict__ bg1,
    const float* __restrict__ wg2, const float* __restrict__ bg2,
    const float* __restrict__ wg3, const float* __restrict__ bg3,
    float* __restrict__ out)
{
    __shared__ __attribute__((aligned(16))) _Float16 xf[2][16 * XSTR]; // 4.6 KB
    __shared__ __attribute__((aligned(16))) _Float16 h1s[16 * 128];    // 4 KB, swizzled
    __shared__ __attribute__((aligned(16))) _Float16 h2s[16 * 128];    // 4 KB, swizzled
    __shared__ __attribute__((aligned(16))) float b1ps[128];
    __shared__ __attribute__((aligned(16))) float pooled[128];
    __shared__ float g1s[128];
    __shared__ float g2s[64];
    __shared__ float swne[96];
    __shared__ float sbne[32];
    __shared__ float sEnc[32];
    __shared__ float red16[16][33];  // +1 pad: conflict-free quad-leader writes

    const int b = blockIdx.x, tid = threadIdx.x;
    const int lane = tid & 63, jq = tid >> 6;
    const int l15 = lane & 15, quad = lane >> 4;

    if (tid < 96) swne[tid] = wne[tid];
    if (tid < 32) sbne[tid] = bne[tid];

    // segment range: precomputed boundary table (uniform scalar loads)
    const int start = seg[b];
    const int end   = seg[b + 1];
    const int n = end - start;
    const int niter = (n + 15) >> 4;
    __syncthreads();

    // ---- encoder + segment max (relu>=0 so init-0 max == neginf->0 guard) ----
    {
        float mx[32];
#pragma unroll
        for (int j = 0; j < 32; j++) mx[j] = 0.f;
        for (int p = start + tid; p < end; p += 256) {
            float x0 = pts[3 * p], x1 = pts[3 * p + 1], x2 = pts[3 * p + 2];
#pragma unroll
            for (int j = 0; j < 32; j++) {
                float e = fmaf(x0, swne[j], fmaf(x1, swne[32 + j], fmaf(x2, swne[64 + j], sbne[j])));
                mx[j] = fmaxf(mx[j], e);
            }
        }
        // in-quad reduce (4 levels), quad leaders -> LDS, final 16-way in LDS
#pragma unroll
        for (int j = 0; j < 32; j++) {
#pragma unroll
            for (int off = 1; off < 16; off <<= 1)
                mx[j] = fmaxf(mx[j], __shfl_xor(mx[j], off, 64));
        }
        if (l15 == 0) {
            const int qi = tid >> 4;   // 0..15
#pragma unroll
            for (int j = 0; j < 32; j++) red16[qi][j] = mx[j];
        }
        __syncthreads();
        if (tid < 32) {
            float m = red16[0][tid];
#pragma unroll
            for (int q = 1; q < 16; q++) m = fmaxf(m, red16[q][tid]);
            sEnc[tid] = m;
        }
        __syncthreads();
        // fold enc through W1's enc rows into per-segment bias (fp32 exact)
        if (tid < 128) {
            float acc = b1[tid];
#pragma unroll 8
            for (int k = 0; k < 32; k++) acc = fmaf(sEnc[k], w1[k * 128 + tid], acc);
            b1ps[tid] = acc;
        }
    }

    // ---- resident weight frags (A operand: row = feature j, k = quad*8+t) ----
    const int jc0 = jq * 32 + l15, jc1 = jc0 + 16;
    half8 w1f[2][2], w2f[2][4], w3f[2][4];
#pragma unroll
    for (int ks = 0; ks < 2; ks++) {
        w1f[0][ks] = *(const half8*)(w1T + jc0 * 64 + ks * 32 + quad * 8);
        w1f[1][ks] = *(const half8*)(w1T + jc1 * 64 + ks * 32 + quad * 8);
    }
#pragma unroll
    for (int ks = 0; ks < 4; ks++) {
        w2f[0][ks] = *(const half8*)(w2T + jc0 * 128 + ks * 32 + quad * 8);
        w2f[1][ks] = *(const half8*)(w2T + jc1 * 128 + ks * 32 + quad * 8);
        w3f[0][ks] = *(const half8*)(w3T + jc0 * 128 + ks * 32 + quad * 8);
        w3f[1][ks] = *(const half8*)(w3T + jc1 * 128 + ks * 32 + quad * 8);
    }
    // per-lane bias quads: acc[jt][i] <-> feature j = jq*32 + jt*16 + quad*4 + i
    const int j0 = jq * 32 + quad * 4;
    floatx4 bb2[2], bb3[2];
    bb2[0] = *(const floatx4*)(b2 + j0); bb2[1] = *(const floatx4*)(b2 + j0 + 16);
    bb3[0] = *(const floatx4*)(b3 + j0); bb3[1] = *(const floatx4*)(b3 + j0 + 16);

    // staging: 1 float4/thread/iter (16 rows x 64 f32)
    const int srow = tid >> 4, scol = tid & 15;
    floatx4 pf;
    auto issue = [&](int it) {
        int p = start + it * 16 + srow;
        if (p < end) pf = *(const floatx4*)(feat + (size_t)p * 64 + scol * 4);
        else         pf = (floatx4){0.f, 0.f, 0.f, 0.f};
    };
    auto commit = [&](int buf) {
        half4 hv = {(_Float16)pf.x, (_Float16)pf.y, (_Float16)pf.z, (_Float16)pf.w};
        *(half4*)(&xf[buf][srow * XSTR + scol * 4]) = hv;
    };
    // transposed-output store: lane holds row=l15, 4 consecutive cols.
    // XOR chunk swizzle (feature-chunk ^ point-row).
    auto storeH = [&](_Float16* hbuf, floatx4* acc) {
#pragma unroll
        for (int jt = 0; jt < 2; jt++) {
            half4 hv = {(_Float16)fmaxf(acc[jt][0], 0.f), (_Float16)fmaxf(acc[jt][1], 0.f),
                        (_Float16)fmaxf(acc[jt][2], 0.f), (_Float16)fmaxf(acc[jt][3], 0.f)};
            const int c = j0 + jt * 16;
            const int off = (l15 << 7) + ((((c >> 3) ^ l15) & 15) << 3) + (c & 7);
            *(half4*)(&hbuf[off]) = hv;
        }
    };

    if (niter > 0) { issue(0); commit(0); if (niter > 1) issue(1); }
    __syncthreads();   // covers b1ps + xf[0]

    floatx4 bb1[2];
    bb1[0] = *(const floatx4*)(b1ps + j0); bb1[1] = *(const floatx4*)(b1ps + j0 + 16);

    floatx4 vm[2];
#pragma unroll
    for (int i = 0; i < 4; i++) { vm[0][i] = 0.f; vm[1][i] = 0.f; }

    for (int it = 0; it < niter; it++) {
        const int buf = it & 1;
        floatx4 acc[2];

        // ---- Layer 1: D = W1^T * x^T (K=64), bias in C-in ----
        acc[0] = bb1[0]; acc[1] = bb1[1];
#pragma unroll
        for (int ks = 0; ks < 2; ks++) {
            half8 a = *(const half8*)(&xf[buf][l15 * XSTR + ks * 32 + quad * 8]);
            acc[0] = __builtin_amdgcn_mfma_f32_16x16x32_f16(w1f[0][ks], a, acc[0], 0, 0, 0);
            acc[1] = __builtin_amdgcn_mfma_f32_16x16x32_f16(w1f[1][ks], a, acc[1], 0, 0, 0);
        }
        storeH(h1s, acc);
        __syncthreads();   // B1: h1 ready

        // ---- Layer 2 (K=128) ----
        acc[0] = bb2[0]; acc[1] = bb2[1];
#pragma unroll
        for (int ks = 0; ks < 4; ks++) {
            half8 a = *(const half8*)(&h1s[(l15 << 7) + ((((ks * 4 + quad) ^ l15) & 15) << 3)]);
            acc[0] = __builtin_amdgcn_mfma_f32_16x16x32_f16(w2f[0][ks], a, acc[0], 0, 0, 0);
            acc[1] = __builtin_amdgcn_mfma_f32_16x16x32_f16(w2f[1][ks], a, acc[1], 0, 0, 0);
        }
        storeH(h2s, acc);
        if (it + 1 < niter) { commit(buf ^ 1); if (it + 2 < niter) issue(it + 2); }
        __syncthreads();   // B2: h2 + next x ready

        // ---- Layer 3 (K=128) -> running max (relu folded: vm>=0) ----
        acc[0] = bb3[0]; acc[1] = bb3[1];
#pragma unroll
        for (int ks = 0; ks < 4; ks++) {
            half8 a = *(const half8*)(&h2s[(l15 << 7) + ((((ks * 4 + quad) ^ l15) & 15) << 3)]);
            acc[0] = __builtin_amdgcn_mfma_f32_16x16x32_f16(w3f[0][ks], a, acc[0], 0, 0, 0);
            acc[1] = __builtin_amdgcn_mfma_f32_16x16x32_f16(w3f[1][ks], a, acc[1], 0, 0, 0);
        }
        if (it * 16 + l15 < n) {   // row = point = l15
#pragma unroll
            for (int i = 0; i < 4; i++) {
                vm[0][i] = fmaxf(vm[0][i], acc[0][i]);
                vm[1][i] = fmaxf(vm[1][i], acc[1][i]);
            }
        }
        // no barrier: h2 reuse fenced by next B1 (reads pre-B1, writes post-B1)
    }

    // reduce over the 16 point-lanes; each feature owned by one (wave,quad)
#pragma unroll
    for (int jt = 0; jt < 2; jt++) {
#pragma unroll
        for (int off = 1; off < 16; off <<= 1) {
#pragma unroll
            for (int i = 0; i < 4; i++)
                vm[jt][i] = fmaxf(vm[jt][i], __shfl_xor(vm[jt][i], off, 64));
        }
    }
    if (l15 == 0) {
        *(floatx4*)(pooled + j0)      = vm[0];
        *(floatx4*)(pooled + j0 + 16) = vm[1];
    }
    __syncthreads();

    // ---- fp32 head MLP (tiny, exact) ----
    if (tid < 128) {
        float acc = bg1[tid];
#pragma unroll 8
        for (int k = 0; k < 128; k++) acc = fmaf(pooled[k], wg1[k * 128 + tid], acc);
        g1s[tid] = fmaxf(acc, 0.f);
    }
    __syncthreads();
    if (tid < 64) {
        float acc = bg2[tid];
#pragma unroll 8
        for (int k = 0; k < 128; k++) acc = fmaf(g1s[k], wg2[k * 64 + tid], acc);
        g2s[tid] = fmaxf(acc, 0.f);
    }
    __syncthreads();
    if (tid < 32) {
        float acc = bg3[tid];
#pragma unroll 8
        for (int k = 0; k < 64; k++) acc = fmaf(g2s[k], wg3[k * 32 + tid], acc);
        out[b * 32 + tid] = fmaxf(acc, 0.f);
    }
}

// ---------------------------------------------------------------------------
extern "C" void kernel_launch(void* const* d_in, const int* in_sizes, int n_in,
                              void* d_out, int out_size, void* d_ws, size_t ws_size,
                              hipStream_t stream) {
    const float* points = (const float*)d_in[0];
    const float* feat   = (const float*)d_in[1];
    const int*   batch  = (const int*)d_in[2];
    const float* w_ne   = (const float*)d_in[3];
    const float* b_ne   = (const float*)d_in[4];
    const float* w1  = (const float*)d_in[5];
    const float* b1  = (const float*)d_in[6];
    const float* w2  = (const float*)d_in[7];
    const float* b2  = (const float*)d_in[8];
    const float* w3  = (const float*)d_in[9];
    const float* b3  = (const float*)d_in[10];
    const float* wg1 = (const float*)d_in[11];
    const float* bg1 = (const float*)d_in[12];
    const float* wg2 = (const float*)d_in[13];
    const float* bg2 = (const float*)d_in[14];
    const float* wg3 = (const float*)d_in[15];
    const float* bg3 = (const float*)d_in[16];
    float* out = (float*)d_out;

    char* ws = (char*)d_ws;
    _Float16* w1T = (_Float16*)ws;                   // 8192  halfs = 16 KiB
    _Float16* w2T = (_Float16*)(ws + 16384);         // 16384 halfs = 32 KiB
    _Float16* w3T = (_Float16*)(ws + 49152);         // 16384 halfs = 32 KiB
    int*      seg = (int*)(ws + 81920);              // 2049 ints ~ 8 KiB

    wconv<<<169, 256, 0, stream>>>(w1, w2, w3, batch, w1T, w2T, w3T, seg);
    fused_all<<<BSEG, 256, 0, stream>>>(points, feat, seg, w_ne, b_ne, w1, b1,
                                        w1T, w2T, w3T, b2, b3,
                                        wg1, bg1, wg2, bg2, wg3, bg3, out);
}

// Round 4
// 483.306 us; speedup vs baseline: 1.3129x; 1.0314x over previous
//
#include <hip/hip_runtime.h>
#include <hip/hip_fp16.h>

// Problem constants (fixed by reference)
#define N_PTS 1048576
#define BSEG  2048
#define XSTR  72    // xf f16 row stride: 64 feats + 8 pad (144 B, bank shift 4/row)
#define MROW  32    // points per main-loop iteration (2 MFMA point-tiles)

typedef _Float16 half8  __attribute__((ext_vector_type(8)));
typedef _Float16 half4  __attribute__((ext_vector_type(4)));
typedef float    floatx4 __attribute__((ext_vector_type(4)));

// ---------------------------------------------------------------------------
// Kernel W: transpose + f16-convert heavy-layer weights, and precompute the
// segment boundary table seg[0..2048] (batch is sorted).
// Index ranges: [0,8192) w1T | [8192,24576) w2T | [24576,40960) w3T
//               [40960,43009) seg
// ---------------------------------------------------------------------------
__global__ __launch_bounds__(256) void wconv(const float* __restrict__ w1,
                                             const float* __restrict__ w2,
                                             const float* __restrict__ w3,
                                             const int* __restrict__ batch,
                                             _Float16* __restrict__ w1T,
                                             _Float16* __restrict__ w2T,
                                             _Float16* __restrict__ w3T,
                                             int* __restrict__ seg) {
    int idx = blockIdx.x * 256 + threadIdx.x;
    if (idx < 8192) {                         // 128*64
        int j = idx >> 6, k = idx & 63;
        w1T[idx] = (_Float16)w1[(32 + k) * 128 + j];
    } else if (idx < 24576) {
        int i = idx - 8192; int j = i >> 7, k = i & 127;
        w2T[i] = (_Float16)w2[k * 128 + j];
    } else if (idx < 40960) {
        int i = idx - 24576; int j = i >> 7, k = i & 127;
        w3T[i] = (_Float16)w3[k * 128 + j];
    } else if (idx < 40960 + 2049) {
        int b = idx - 40960;
        if (b == 2048) {
            seg[2048] = N_PTS;
        } else {
            int lo = 0, hi = N_PTS;
            while (lo < hi) { int mid = (lo + hi) >> 1; if (batch[mid] < b) lo = mid + 1; else hi = mid; }
            seg[b] = lo;
        }
    }
}

// ---------------------------------------------------------------------------
// Mega kernel: per-segment encoder + pool + bias-fold + 3-layer f16 MFMA MLP
// + segment max + fp32 head. One block per segment, 4 waves.
//
// Round-3 postmortem: latency/barrier-bound (~1900 cyc per 16-row iter, only
// ~3 blocks/CU resident at ~164 unified VGPR+AGPR). This round: M=32 rows per
// iteration (2 point-tiles per layer phase) -> halves barrier count and the
// per-point share of sync/latency overhead; doubles feat bytes in flight.
//
// MFMA layers computed TRANSPOSED: D = W^T (A) * x^T (B). Each lane holds
// point = row-tile + lane&15 (output col) and 4 consecutive features per quad.
// h stores are a single half4 into the XOR chunk-swizzled [32][128] layout;
// reads use the matching swizzle (reads conflict-free; stores 2-way, ~7 us,
// unfixable without re-adding DPP packing VALU). Biases ride in the MFMA
// C-in; L3 relu folds into the >=0 running max. w1f/w2f/w3f VGPR-resident.
// ---------------------------------------------------------------------------
__global__ __launch_bounds__(256, 3) void fused_all(
    const float* __restrict__ pts, const float* __restrict__ feat,
    const int* __restrict__ seg,
    const float* __restrict__ wne, const float* __restrict__ bne,
    const float* __restrict__ w1, const float* __restrict__ b1,
    const _Float16* __restrict__ w1T, const _Float16* __restrict__ w2T,
    const _Float16* __restrict__ w3T,
    const float* __restrict__ b2, const float* __restrict__ b3,
    const float* __restrict__ wg1, const float* __restrict__ bg1,
    const float* __restrict__ wg2, const float* __restrict__ bg2,
    const float* __restrict__ wg3, const float* __restrict__ bg3,
    float* __restrict__ out)
{
    __shared__ __attribute__((aligned(16))) _Float16 xf[2][MROW * XSTR]; // 9.2 KB
    __shared__ __attribute__((aligned(16))) _Float16 h1s[MROW * 128];    // 8 KB, swizzled
    __shared__ __attribute__((aligned(16))) _Float16 h2s[MROW * 128];    // 8 KB, swizzled
    __shared__ __attribute__((aligned(16))) float b1ps[128];
    __shared__ __attribute__((aligned(16))) float pooled[128];
    __shared__ float g1s[128];
    __shared__ float g2s[64];
    __shared__ float swne[96];
    __shared__ float sbne[32];
    __shared__ float sEnc[32];
    __shared__ float red16[16][33];  // +1 pad: conflict-free quad-leader writes

    const int b = blockIdx.x, tid = threadIdx.x;
    const int lane = tid & 63, jq = tid >> 6;
    const int l15 = lane & 15, quad = lane >> 4;

    if (tid < 96) swne[tid] = wne[tid];
    if (tid < 32) sbne[tid] = bne[tid];

    // segment range: precomputed boundary table (uniform scalar loads)
    const int start = seg[b];
    const int end   = seg[b + 1];
    const int n = end - start;
    const int niter = (n + MROW - 1) >> 5;
    __syncthreads();

    // ---- encoder + segment max (relu>=0 so init-0 max == neginf->0 guard) ----
    {
        float mx[32];
#pragma unroll
        for (int j = 0; j < 32; j++) mx[j] = 0.f;
        for (int p = start + tid; p < end; p += 256) {
            float x0 = pts[3 * p], x1 = pts[3 * p + 1], x2 = pts[3 * p + 2];
#pragma unroll
            for (int j = 0; j < 32; j++) {
                float e = fmaf(x0, swne[j], fmaf(x1, swne[32 + j], fmaf(x2, swne[64 + j], sbne[j])));
                mx[j] = fmaxf(mx[j], e);
            }
        }
        // in-quad reduce (4 levels), quad leaders -> LDS, final 16-way in LDS
#pragma unroll
        for (int j = 0; j < 32; j++) {
#pragma unroll
            for (int off = 1; off < 16; off <<= 1)
                mx[j] = fmaxf(mx[j], __shfl_xor(mx[j], off, 64));
        }
        if (l15 == 0) {
            const int qi = tid >> 4;   // 0..15
#pragma unroll
            for (int j = 0; j < 32; j++) red16[qi][j] = mx[j];
        }
        __syncthreads();
        if (tid < 32) {
            float m = red16[0][tid];
#pragma unroll
            for (int q = 1; q < 16; q++) m = fmaxf(m, red16[q][tid]);
            sEnc[tid] = m;
        }
        __syncthreads();
        // fold enc through W1's enc rows into per-segment bias (fp32 exact)
        if (tid < 128) {
            float acc = b1[tid];
#pragma unroll 8
            for (int k = 0; k < 32; k++) acc = fmaf(sEnc[k], w1[k * 128 + tid], acc);
            b1ps[tid] = acc;
        }
    }

    // ---- resident weight frags (A operand: row = feature j, k = quad*8+t) ----
    const int jc0 = jq * 32 + l15, jc1 = jc0 + 16;
    half8 w1f[2][2], w2f[2][4], w3f[2][4];
#pragma unroll
    for (int ks = 0; ks < 2; ks++) {
        w1f[0][ks] = *(const half8*)(w1T + jc0 * 64 + ks * 32 + quad * 8);
        w1f[1][ks] = *(const half8*)(w1T + jc1 * 64 + ks * 32 + quad * 8);
    }
#pragma unroll
    for (int ks = 0; ks < 4; ks++) {
        w2f[0][ks] = *(const half8*)(w2T + jc0 * 128 + ks * 32 + quad * 8);
        w2f[1][ks] = *(const half8*)(w2T + jc1 * 128 + ks * 32 + quad * 8);
        w3f[0][ks] = *(const half8*)(w3T + jc0 * 128 + ks * 32 + quad * 8);
        w3f[1][ks] = *(const half8*)(w3T + jc1 * 128 + ks * 32 + quad * 8);
    }
    // per-lane bias quads: acc[jt][i] <-> feature j = jq*32 + jt*16 + quad*4 + i
    const int j0 = jq * 32 + quad * 4;
    floatx4 bb2[2], bb3[2];
    bb2[0] = *(const floatx4*)(b2 + j0); bb2[1] = *(const floatx4*)(b2 + j0 + 16);
    bb3[0] = *(const floatx4*)(b3 + j0); bb3[1] = *(const floatx4*)(b3 + j0 + 16);

    // staging: 2 float4/thread/iter (32 rows x 64 f32 = 8 KB/block-iter)
    const int srow = tid >> 4, scol = tid & 15;
    floatx4 pf0, pf1;
    auto issue = [&](int it) {
        int p0 = start + it * MROW + srow;
        int p1 = p0 + 16;
        pf0 = (p0 < end) ? *(const floatx4*)(feat + (size_t)p0 * 64 + scol * 4)
                         : (floatx4){0.f, 0.f, 0.f, 0.f};
        pf1 = (p1 < end) ? *(const floatx4*)(feat + (size_t)p1 * 64 + scol * 4)
                         : (floatx4){0.f, 0.f, 0.f, 0.f};
    };
    auto commit = [&](int buf) {
        half4 hv0 = {(_Float16)pf0.x, (_Float16)pf0.y, (_Float16)pf0.z, (_Float16)pf0.w};
        half4 hv1 = {(_Float16)pf1.x, (_Float16)pf1.y, (_Float16)pf1.z, (_Float16)pf1.w};
        *(half4*)(&xf[buf][srow * XSTR + scol * 4])        = hv0;
        *(half4*)(&xf[buf][(srow + 16) * XSTR + scol * 4]) = hv1;
    };
    // transposed-output store: lane holds row (point), 4 consecutive cols.
    // XOR chunk swizzle (feature-chunk ^ point-row), bijective per row.
    auto storeH = [&](_Float16* hbuf, floatx4* acc, int row) {
#pragma unroll
        for (int jt = 0; jt < 2; jt++) {
            half4 hv = {(_Float16)fmaxf(acc[jt][0], 0.f), (_Float16)fmaxf(acc[jt][1], 0.f),
                        (_Float16)fmaxf(acc[jt][2], 0.f), (_Float16)fmaxf(acc[jt][3], 0.f)};
            const int c = j0 + jt * 16;
            const int off = (row << 7) + ((((c >> 3) ^ row) & 15) << 3) + (c & 7);
            *(half4*)(&hbuf[off]) = hv;
        }
    };

    if (niter > 0) { issue(0); commit(0); if (niter > 1) issue(1); }
    __syncthreads();   // covers b1ps + xf[0]

    floatx4 bb1[2];
    bb1[0] = *(const floatx4*)(b1ps + j0); bb1[1] = *(const floatx4*)(b1ps + j0 + 16);

    floatx4 vm[2];
#pragma unroll
    for (int i = 0; i < 4; i++) { vm[0][i] = 0.f; vm[1][i] = 0.f; }

    for (int it = 0; it < niter; it++) {
        const int buf = it & 1;
        floatx4 acc[2];

        // ---- Layer 1: D = W1^T * x^T (K=64), bias in C-in, 2 point-tiles ----
#pragma unroll
        for (int pt = 0; pt < 2; pt++) {
            const int row = pt * 16 + l15;
            acc[0] = bb1[0]; acc[1] = bb1[1];
#pragma unroll
            for (int ks = 0; ks < 2; ks++) {
                half8 a = *(const half8*)(&xf[buf][row * XSTR + ks * 32 + quad * 8]);
                acc[0] = __builtin_amdgcn_mfma_f32_16x16x32_f16(w1f[0][ks], a, acc[0], 0, 0, 0);
                acc[1] = __builtin_amdgcn_mfma_f32_16x16x32_f16(w1f[1][ks], a, acc[1], 0, 0, 0);
            }
            storeH(h1s, acc, row);
        }
        __syncthreads();   // B1: h1 ready

        // ---- Layer 2 (K=128), 2 point-tiles ----
#pragma unroll
        for (int pt = 0; pt < 2; pt++) {
            const int row = pt * 16 + l15;
            acc[0] = bb2[0]; acc[1] = bb2[1];
#pragma unroll
            for (int ks = 0; ks < 4; ks++) {
                half8 a = *(const half8*)(&h1s[(row << 7) + ((((ks * 4 + quad) ^ row) & 15) << 3)]);
                acc[0] = __builtin_amdgcn_mfma_f32_16x16x32_f16(w2f[0][ks], a, acc[0], 0, 0, 0);
                acc[1] = __builtin_amdgcn_mfma_f32_16x16x32_f16(w2f[1][ks], a, acc[1], 0, 0, 0);
            }
            storeH(h2s, acc, row);
        }
        if (it + 1 < niter) { commit(buf ^ 1); if (it + 2 < niter) issue(it + 2); }
        __syncthreads();   // B2: h2 + next x ready

        // ---- Layer 3 (K=128) -> running max (relu folded: vm>=0) ----
#pragma unroll
        for (int pt = 0; pt < 2; pt++) {
            const int row = pt * 16 + l15;
            acc[0] = bb3[0]; acc[1] = bb3[1];
#pragma unroll
            for (int ks = 0; ks < 4; ks++) {
                half8 a = *(const half8*)(&h2s[(row << 7) + ((((ks * 4 + quad) ^ row) & 15) << 3)]);
                acc[0] = __builtin_amdgcn_mfma_f32_16x16x32_f16(w3f[0][ks], a, acc[0], 0, 0, 0);
                acc[1] = __builtin_amdgcn_mfma_f32_16x16x32_f16(w3f[1][ks], a, acc[1], 0, 0, 0);
            }
            if (it * MROW + row < n) {   // row = point (col of D)
#pragma unroll
                for (int i = 0; i < 4; i++) {
                    vm[0][i] = fmaxf(vm[0][i], acc[0][i]);
                    vm[1][i] = fmaxf(vm[1][i], acc[1][i]);
                }
            }
        }
        // no barrier: h2 reuse fenced by next B1 (reads pre-B1, writes post-B1)
    }

    // reduce over the 16 point-lanes; each feature owned by one (wave,quad)
#pragma unroll
    for (int jt = 0; jt < 2; jt++) {
#pragma unroll
        for (int off = 1; off < 16; off <<= 1) {
#pragma unroll
            for (int i = 0; i < 4; i++)
                vm[jt][i] = fmaxf(vm[jt][i], __shfl_xor(vm[jt][i], off, 64));
        }
    }
    if (l15 == 0) {
        *(floatx4*)(pooled + j0)      = vm[0];
        *(floatx4*)(pooled + j0 + 16) = vm[1];
    }
    __syncthreads();

    // ---- fp32 head MLP (tiny, exact) ----
    if (tid < 128) {
        float acc = bg1[tid];
#pragma unroll 8
        for (int k = 0; k < 128; k++) acc = fmaf(pooled[k], wg1[k * 128 + tid], acc);
        g1s[tid] = fmaxf(acc, 0.f);
    }
    __syncthreads();
    if (tid < 64) {
        float acc = bg2[tid];
#pragma unroll 8
        for (int k = 0; k < 128; k++) acc = fmaf(g1s[k], wg2[k * 64 + tid], acc);
        g2s[tid] = fmaxf(acc, 0.f);
    }
    __syncthreads();
    if (tid < 32) {
        float acc = bg3[tid];
#pragma unroll 8
        for (int k = 0; k < 64; k++) acc = fmaf(g2s[k], wg3[k * 32 + tid], acc);
        out[b * 32 + tid] = fmaxf(acc, 0.f);
    }
}

// ---------------------------------------------------------------------------
extern "C" void kernel_launch(void* const* d_in, const int* in_sizes, int n_in,
                              void* d_out, int out_size, void* d_ws, size_t ws_size,
                              hipStream_t stream) {
    const float* points = (const float*)d_in[0];
    const float* feat   = (const float*)d_in[1];
    const int*   batch  = (const int*)d_in[2];
    const float* w_ne   = (const float*)d_in[3];
    const float* b_ne   = (const float*)d_in[4];
    const float* w1  = (const float*)d_in[5];
    const float* b1  = (const float*)d_in[6];
    const float* w2  = (const float*)d_in[7];
    const float* b2  = (const float*)d_in[8];
    const float* w3  = (const float*)d_in[9];
    const float* b3  = (const float*)d_in[10];
    const float* wg1 = (const float*)d_in[11];
    const float* bg1 = (const float*)d_in[12];
    const float* wg2 = (const float*)d_in[13];
    const float* bg2 = (const float*)d_in[14];
    const float* wg3 = (const float*)d_in[15];
    const float* bg3 = (const float*)d_in[16];
    float* out = (float*)d_out;

    char* ws = (char*)d_ws;
    _Float16* w1T = (_Float16*)ws;                   // 8192  halfs = 16 KiB
    _Float16* w2T = (_Float16*)(ws + 16384);         // 16384 halfs = 32 KiB
    _Float16* w3T = (_Float16*)(ws + 49152);         // 16384 halfs = 32 KiB
    int*      seg = (int*)(ws + 81920);              // 2049 ints ~ 8 KiB

    wconv<<<169, 256, 0, stream>>>(w1, w2, w3, batch, w1T, w2T, w3T, seg);
    fused_all<<<BSEG, 256, 0, stream>>>(points, feat, seg, w_ne, b_ne, w1, b1,
                                        w1T, w2T, w3T, b2, b3,
                                        wg1, bg1, wg2, bg2, wg3, bg3, out);
}

// Round 5
// 481.521 us; speedup vs baseline: 1.3178x; 1.0037x over previous
//
#include <hip/hip_runtime.h>
#include <hip/hip_fp16.h>

// Problem constants (fixed by reference)
#define N_PTS 1048576
#define BSEG  2048
#define XSTR  72    // xf f16 row stride: 64 feats + 8 pad (144 B, bank shift 4/row)
#define MROW  32    // points per main-loop iteration (2 MFMA point-tiles)

typedef _Float16 half8  __attribute__((ext_vector_type(8)));
typedef _Float16 half4  __attribute__((ext_vector_type(4)));
typedef float    floatx4 __attribute__((ext_vector_type(4)));

// LDS-only barrier: __syncthreads() drains vmcnt(0) too, which serializes the
// just-issued HBM feat prefetch into every barrier (~900 cyc, zero cover —
// the m97 lesson). Cross-wave deps at the in-loop barriers are LDS only, so
// wait lgkmcnt(0) and let global loads stay in flight until their register
// use (compiler inserts the per-register vmcnt wait at commit()).
// sched_barrier(0) fences machine-sched movement (pitfall: hipcc hoists
// register-only ops past inline-asm waits); "memory" clobber fences IR.
#define BAR_LGKM() do {                                      \
    __builtin_amdgcn_sched_barrier(0);                       \
    asm volatile("s_waitcnt lgkmcnt(0)" ::: "memory");       \
    __builtin_amdgcn_s_barrier();                            \
    __builtin_amdgcn_sched_barrier(0);                       \
} while (0)

// ---------------------------------------------------------------------------
// Kernel W: transpose + f16-convert heavy-layer weights, and precompute the
// segment boundary table seg[0..2048] (batch is sorted).
// Index ranges: [0,8192) w1T | [8192,24576) w2T | [24576,40960) w3T
//               [40960,43009) seg
// ---------------------------------------------------------------------------
__global__ __launch_bounds__(256) void wconv(const float* __restrict__ w1,
                                             const float* __restrict__ w2,
                                             const float* __restrict__ w3,
                                             const int* __restrict__ batch,
                                             _Float16* __restrict__ w1T,
                                             _Float16* __restrict__ w2T,
                                             _Float16* __restrict__ w3T,
                                             int* __restrict__ seg) {
    int idx = blockIdx.x * 256 + threadIdx.x;
    if (idx < 8192) {                         // 128*64
        int j = idx >> 6, k = idx & 63;
        w1T[idx] = (_Float16)w1[(32 + k) * 128 + j];
    } else if (idx < 24576) {
        int i = idx - 8192; int j = i >> 7, k = i & 127;
        w2T[i] = (_Float16)w2[k * 128 + j];
    } else if (idx < 40960) {
        int i = idx - 24576; int j = i >> 7, k = i & 127;
        w3T[i] = (_Float16)w3[k * 128 + j];
    } else if (idx < 40960 + 2049) {
        int b = idx - 40960;
        if (b == 2048) {
            seg[2048] = N_PTS;
        } else {
            int lo = 0, hi = N_PTS;
            while (lo < hi) { int mid = (lo + hi) >> 1; if (batch[mid] < b) lo = mid + 1; else hi = mid; }
            seg[b] = lo;
        }
    }
}

// ---------------------------------------------------------------------------
// Mega kernel: per-segment encoder + pool + bias-fold + 3-layer f16 MFMA MLP
// + segment max + fp32 head. One block per segment, 4 waves, M=32 rows/iter.
//
// Round-4 postmortem: latency-bound; the dominant per-iter stall was the
// vmcnt(0) drain __syncthreads() forces right after the feat prefetch issue.
// This round: in-loop barriers are lgkmcnt-only (BAR_LGKM) so the prefetch
// rides across B2->L3->L1->L2 (~3 phases of cover) and is waited on only at
// commit's register use. Everything else identical to round 4 (clean A/B).
//
// MFMA layers computed TRANSPOSED: D = W^T (A) * x^T (B). Each lane holds
// point = row-tile + lane&15 (output col) and 4 consecutive features per quad.
// h stores are a single half4 into the XOR chunk-swizzled [32][128] layout;
// reads use the matching swizzle. Biases ride in the MFMA C-in; L3 relu folds
// into the >=0 running max. w1f/w2f/w3f VGPR-resident.
// ---------------------------------------------------------------------------
__global__ __launch_bounds__(256, 3) void fused_all(
    const float* __restrict__ pts, const float* __restrict__ feat,
    const int* __restrict__ seg,
    const float* __restrict__ wne, const float* __restrict__ bne,
    const float* __restrict__ w1, const float* __restrict__ b1,
    const _Float16* __restrict__ w1T, const _Float16* __restrict__ w2T,
    const _Float16* __restrict__ w3T,
    const float* __restrict__ b2, const float* __restrict__ b3,
    const float* __restrict__ wg1, const float* __restrict__ bg1,
    const float* __restrict__ wg2, const float* __restrict__ bg2,
    const float* __restrict__ wg3, const float* __restrict__ bg3,
    float* __restrict__ out)
{
    __shared__ __attribute__((aligned(16))) _Float16 xf[2][MROW * XSTR]; // 9.2 KB
    __shared__ __attribute__((aligned(16))) _Float16 h1s[MROW * 128];    // 8 KB, swizzled
    __shared__ __attribute__((aligned(16))) _Float16 h2s[MROW * 128];    // 8 KB, swizzled
    __shared__ __attribute__((aligned(16))) float b1ps[128];
    __shared__ __attribute__((aligned(16))) float pooled[128];
    __shared__ float g1s[128];
    __shared__ float g2s[64];
    __shared__ float swne[96];
    __shared__ float sbne[32];
    __shared__ float sEnc[32];
    __shared__ float red16[16][33];  // +1 pad: conflict-free quad-leader writes

    const int b = blockIdx.x, tid = threadIdx.x;
    const int lane = tid & 63, jq = tid >> 6;
    const int l15 = lane & 15, quad = lane >> 4;

    if (tid < 96) swne[tid] = wne[tid];
    if (tid < 32) sbne[tid] = bne[tid];

    // segment range: precomputed boundary table (uniform scalar loads)
    const int start = seg[b];
    const int end   = seg[b + 1];
    const int n = end - start;
    const int niter = (n + MROW - 1) >> 5;
    __syncthreads();

    // ---- encoder + segment max (relu>=0 so init-0 max == neginf->0 guard) ----
    {
        float mx[32];
#pragma unroll
        for (int j = 0; j < 32; j++) mx[j] = 0.f;
        for (int p = start + tid; p < end; p += 256) {
            float x0 = pts[3 * p], x1 = pts[3 * p + 1], x2 = pts[3 * p + 2];
#pragma unroll
            for (int j = 0; j < 32; j++) {
                float e = fmaf(x0, swne[j], fmaf(x1, swne[32 + j], fmaf(x2, swne[64 + j], sbne[j])));
                mx[j] = fmaxf(mx[j], e);
            }
        }
        // in-quad reduce (4 levels), quad leaders -> LDS, final 16-way in LDS
#pragma unroll
        for (int j = 0; j < 32; j++) {
#pragma unroll
            for (int off = 1; off < 16; off <<= 1)
                mx[j] = fmaxf(mx[j], __shfl_xor(mx[j], off, 64));
        }
        if (l15 == 0) {
            const int qi = tid >> 4;   // 0..15
#pragma unroll
            for (int j = 0; j < 32; j++) red16[qi][j] = mx[j];
        }
        __syncthreads();
        if (tid < 32) {
            float m = red16[0][tid];
#pragma unroll
            for (int q = 1; q < 16; q++) m = fmaxf(m, red16[q][tid]);
            sEnc[tid] = m;
        }
        __syncthreads();
        // fold enc through W1's enc rows into per-segment bias (fp32 exact)
        if (tid < 128) {
            float acc = b1[tid];
#pragma unroll 8
            for (int k = 0; k < 32; k++) acc = fmaf(sEnc[k], w1[k * 128 + tid], acc);
            b1ps[tid] = acc;
        }
    }

    // ---- resident weight frags (A operand: row = feature j, k = quad*8+t) ----
    const int jc0 = jq * 32 + l15, jc1 = jc0 + 16;
    half8 w1f[2][2], w2f[2][4], w3f[2][4];
#pragma unroll
    for (int ks = 0; ks < 2; ks++) {
        w1f[0][ks] = *(const half8*)(w1T + jc0 * 64 + ks * 32 + quad * 8);
        w1f[1][ks] = *(const half8*)(w1T + jc1 * 64 + ks * 32 + quad * 8);
    }
#pragma unroll
    for (int ks = 0; ks < 4; ks++) {
        w2f[0][ks] = *(const half8*)(w2T + jc0 * 128 + ks * 32 + quad * 8);
        w2f[1][ks] = *(const half8*)(w2T + jc1 * 128 + ks * 32 + quad * 8);
        w3f[0][ks] = *(const half8*)(w3T + jc0 * 128 + ks * 32 + quad * 8);
        w3f[1][ks] = *(const half8*)(w3T + jc1 * 128 + ks * 32 + quad * 8);
    }
    // per-lane bias quads: acc[jt][i] <-> feature j = jq*32 + jt*16 + quad*4 + i
    const int j0 = jq * 32 + quad * 4;
    floatx4 bb2[2], bb3[2];
    bb2[0] = *(const floatx4*)(b2 + j0); bb2[1] = *(const floatx4*)(b2 + j0 + 16);
    bb3[0] = *(const floatx4*)(b3 + j0); bb3[1] = *(const floatx4*)(b3 + j0 + 16);

    // staging: 2 float4/thread/iter (32 rows x 64 f32 = 8 KB/block-iter)
    const int srow = tid >> 4, scol = tid & 15;
    floatx4 pf0, pf1;
    auto issue = [&](int it) {
        int p0 = start + it * MROW + srow;
        int p1 = p0 + 16;
        pf0 = (p0 < end) ? *(const floatx4*)(feat + (size_t)p0 * 64 + scol * 4)
                         : (floatx4){0.f, 0.f, 0.f, 0.f};
        pf1 = (p1 < end) ? *(const floatx4*)(feat + (size_t)p1 * 64 + scol * 4)
                         : (floatx4){0.f, 0.f, 0.f, 0.f};
    };
    auto commit = [&](int buf) {
        half4 hv0 = {(_Float16)pf0.x, (_Float16)pf0.y, (_Float16)pf0.z, (_Float16)pf0.w};
        half4 hv1 = {(_Float16)pf1.x, (_Float16)pf1.y, (_Float16)pf1.z, (_Float16)pf1.w};
        *(half4*)(&xf[buf][srow * XSTR + scol * 4])        = hv0;
        *(half4*)(&xf[buf][(srow + 16) * XSTR + scol * 4]) = hv1;
    };
    // transposed-output store: lane holds row (point), 4 consecutive cols.
    // XOR chunk swizzle (feature-chunk ^ point-row), bijective per row.
    auto storeH = [&](_Float16* hbuf, floatx4* acc, int row) {
#pragma unroll
        for (int jt = 0; jt < 2; jt++) {
            half4 hv = {(_Float16)fmaxf(acc[jt][0], 0.f), (_Float16)fmaxf(acc[jt][1], 0.f),
                        (_Float16)fmaxf(acc[jt][2], 0.f), (_Float16)fmaxf(acc[jt][3], 0.f)};
            const int c = j0 + jt * 16;
            const int off = (row << 7) + ((((c >> 3) ^ row) & 15) << 3) + (c & 7);
            *(half4*)(&hbuf[off]) = hv;
        }
    };

    if (niter > 0) { issue(0); commit(0); if (niter > 1) issue(1); }
    __syncthreads();   // full drain (one-time): covers b1ps + xf[0]

    floatx4 bb1[2];
    bb1[0] = *(const floatx4*)(b1ps + j0); bb1[1] = *(const floatx4*)(b1ps + j0 + 16);

    floatx4 vm[2];
#pragma unroll
    for (int i = 0; i < 4; i++) { vm[0][i] = 0.f; vm[1][i] = 0.f; }

    for (int it = 0; it < niter; it++) {
        const int buf = it & 1;
        floatx4 acc[2];

        // ---- Layer 1: D = W1^T * x^T (K=64), bias in C-in, 2 point-tiles ----
#pragma unroll
        for (int pt = 0; pt < 2; pt++) {
            const int row = pt * 16 + l15;
            acc[0] = bb1[0]; acc[1] = bb1[1];
#pragma unroll
            for (int ks = 0; ks < 2; ks++) {
                half8 a = *(const half8*)(&xf[buf][row * XSTR + ks * 32 + quad * 8]);
                acc[0] = __builtin_amdgcn_mfma_f32_16x16x32_f16(w1f[0][ks], a, acc[0], 0, 0, 0);
                acc[1] = __builtin_amdgcn_mfma_f32_16x16x32_f16(w1f[1][ks], a, acc[1], 0, 0, 0);
            }
            storeH(h1s, acc, row);
        }
        BAR_LGKM();   // B1: h1 ready (LDS only; feat prefetch stays in flight)

        // ---- Layer 2 (K=128), 2 point-tiles ----
#pragma unroll
        for (int pt = 0; pt < 2; pt++) {
            const int row = pt * 16 + l15;
            acc[0] = bb2[0]; acc[1] = bb2[1];
#pragma unroll
            for (int ks = 0; ks < 4; ks++) {
                half8 a = *(const half8*)(&h1s[(row << 7) + ((((ks * 4 + quad) ^ row) & 15) << 3)]);
                acc[0] = __builtin_amdgcn_mfma_f32_16x16x32_f16(w2f[0][ks], a, acc[0], 0, 0, 0);
                acc[1] = __builtin_amdgcn_mfma_f32_16x16x32_f16(w2f[1][ks], a, acc[1], 0, 0, 0);
            }
            storeH(h2s, acc, row);
        }
        if (it + 1 < niter) { commit(buf ^ 1); if (it + 2 < niter) issue(it + 2); }
        BAR_LGKM();   // B2: h2 + next x ready (LDS only; issue() not drained)

        // ---- Layer 3 (K=128) -> running max (relu folded: vm>=0) ----
#pragma unroll
        for (int pt = 0; pt < 2; pt++) {
            const int row = pt * 16 + l15;
            acc[0] = bb3[0]; acc[1] = bb3[1];
#pragma unroll
            for (int ks = 0; ks < 4; ks++) {
                half8 a = *(const half8*)(&h2s[(row << 7) + ((((ks * 4 + quad) ^ row) & 15) << 3)]);
                acc[0] = __builtin_amdgcn_mfma_f32_16x16x32_f16(w3f[0][ks], a, acc[0], 0, 0, 0);
                acc[1] = __builtin_amdgcn_mfma_f32_16x16x32_f16(w3f[1][ks], a, acc[1], 0, 0, 0);
            }
            if (it * MROW + row < n) {   // row = point (col of D)
#pragma unroll
                for (int i = 0; i < 4; i++) {
                    vm[0][i] = fmaxf(vm[0][i], acc[0][i]);
                    vm[1][i] = fmaxf(vm[1][i], acc[1][i]);
                }
            }
        }
        // no barrier: h2 reuse fenced by next B1 (reads pre-B1, writes post-B1)
    }

    // reduce over the 16 point-lanes; each feature owned by one (wave,quad)
#pragma unroll
    for (int jt = 0; jt < 2; jt++) {
#pragma unroll
        for (int off = 1; off < 16; off <<= 1) {
#pragma unroll
            for (int i = 0; i < 4; i++)
                vm[jt][i] = fmaxf(vm[jt][i], __shfl_xor(vm[jt][i], off, 64));
        }
    }
    if (l15 == 0) {
        *(floatx4*)(pooled + j0)      = vm[0];
        *(floatx4*)(pooled + j0 + 16) = vm[1];
    }
    __syncthreads();

    // ---- fp32 head MLP (tiny, exact) ----
    if (tid < 128) {
        float acc = bg1[tid];
#pragma unroll 8
        for (int k = 0; k < 128; k++) acc = fmaf(pooled[k], wg1[k * 128 + tid], acc);
        g1s[tid] = fmaxf(acc, 0.f);
    }
    __syncthreads();
    if (tid < 64) {
        float acc = bg2[tid];
#pragma unroll 8
        for (int k = 0; k < 128; k++) acc = fmaf(g1s[k], wg2[k * 64 + tid], acc);
        g2s[tid] = fmaxf(acc, 0.f);
    }
    __syncthreads();
    if (tid < 32) {
        float acc = bg3[tid];
#pragma unroll 8
        for (int k = 0; k < 64; k++) acc = fmaf(g2s[k], wg3[k * 32 + tid], acc);
        out[b * 32 + tid] = fmaxf(acc, 0.f);
    }
}

// ---------------------------------------------------------------------------
extern "C" void kernel_launch(void* const* d_in, const int* in_sizes, int n_in,
                              void* d_out, int out_size, void* d_ws, size_t ws_size,
                              hipStream_t stream) {
    const float* points = (const float*)d_in[0];
    const float* feat   = (const float*)d_in[1];
    const int*   batch  = (const int*)d_in[2];
    const float* w_ne   = (const float*)d_in[3];
    const float* b_ne   = (const float*)d_in[4];
    const float* w1  = (const float*)d_in[5];
    const float* b1  = (const float*)d_in[6];
    const float* w2  = (const float*)d_in[7];
    const float* b2  = (const float*)d_in[8];
    const float* w3  = (const float*)d_in[9];
    const float* b3  = (const float*)d_in[10];
    const float* wg1 = (const float*)d_in[11];
    const float* bg1 = (const float*)d_in[12];
    const float* wg2 = (const float*)d_in[13];
    const float* bg2 = (const float*)d_in[14];
    const float* wg3 = (const float*)d_in[15];
    const float* bg3 = (const float*)d_in[16];
    float* out = (float*)d_out;

    char* ws = (char*)d_ws;
    _Float16* w1T = (_Float16*)ws;                   // 8192  halfs = 16 KiB
    _Float16* w2T = (_Float16*)(ws + 16384);         // 16384 halfs = 32 KiB
    _Float16* w3T = (_Float16*)(ws + 49152);         // 16384 halfs = 32 KiB
    int*      seg = (int*)(ws + 81920);              // 2049 ints ~ 8 KiB

    wconv<<<169, 256, 0, stream>>>(w1, w2, w3, batch, w1T, w2T, w3T, seg);
    fused_all<<<BSEG, 256, 0, stream>>>(points, feat, seg, w_ne, b_ne, w1, b1,
                                        w1T, w2T, w3T, b2, b3,
                                        wg1, bg1, wg2, bg2, wg3, bg3, out);
}